// Round 10
// baseline (214.363 us; speedup 1.0000x reference)
//
#include <hip/hip_runtime.h>
#include <math.h>

// Problem constants (from reference)
#define NPATCH 8192
#define KC     10
#define DIN    1024
#define DH     512
#define DA     256
#define NCLS   4

#define TM  32    // patches per phi block (full 512-col width per block)
#define LDA 520   // padded LDS row stride (u16): 1040 B spreads b128 frag reads

typedef unsigned short u16;
typedef short bf16x8 __attribute__((ext_vector_type(8)));   // 8 bf16 = 4 VGPRs
typedef float f32x4  __attribute__((ext_vector_type(4)));

// Workspace layout (bytes)
#define OFF_CNT   0                  // int[KC] (40B) + bar[3] @40; 64B memset covers
#define OFF_BAR   40
#define OFF_IDX   64                 // int[KC*NPATCH] sparse (k*NPATCH+slot)
#define OFF_PSUM  327744             // float[KC*DH]
#define OFF_H     348224             // float[KC*DH]
#define OFF_S     368704             // float[KC]
#define OFF_H2    368768             // float[DA]
#define OFF_W1P   369792             // u16[KC*DIN*DH]
#define OFF_W2P   10855552           // u16[KC*DH*DH]
// total ~16.1 MB

__device__ __forceinline__ u16 f2bf(float f) {
  union { float f; unsigned u; } v; v.f = f;
  unsigned r = (v.u + 0x7fffu + ((v.u >> 16) & 1u)) >> 16;  // RNE
  return (u16)r;
}

struct __align__(8) U16x4 { u16 x, y, z, w; };

#define W1_TILES (KC * (DIN / 32) * (DH / 32))  // 5120
#define W2_TILES (KC * (DH / 32) * (DH / 32))   // 2560
#define NB_BUCKET 32
#define NB_PREP   (NB_BUCKET + W1_TILES + W2_TILES)  // 7712

// prep: bucket + zero psum/sstore (blocks 0..31), pack W1/W2 -> bf16 MFMA-B
// panels [k][kb][n][ki]. Fully independent blocks (no x packing).
__global__ __launch_bounds__(256) void prep_kernel(
    const int* __restrict__ cid, int* __restrict__ cnt,
    int* __restrict__ idxlist, const float* __restrict__ W1,
    const float* __restrict__ W2, u16* __restrict__ W1p,
    u16* __restrict__ W2p, float* __restrict__ psum,
    float* __restrict__ sstore) {
  int b = blockIdx.x, t = threadIdx.x;
  if (b < NB_BUCKET) {
    int g = b * 256 + t;
    if (g < KC * DH) psum[g] = 0.f;
    if (g < KC) sstore[g] = 0.f;
    __shared__ int lcnt[KC], lbase[KC];
    if (t < KC) lcnt[t] = 0;
    __syncthreads();
    int n = b * 256 + t;                 // NPATCH == 32*256
    int k = cid[n];
    int myoff = atomicAdd(&lcnt[k], 1);
    __syncthreads();
    if (t < KC) lbase[t] = atomicAdd(&cnt[t], lcnt[t]);
    __syncthreads();
    idxlist[k * NPATCH + lbase[k] + myoff] = n;
  } else {
    __shared__ u16 tile[32][33];
    int bb = b - NB_BUCKET;
    const float* src;
    u16* dst;
    if (bb < W1_TILES) {
      int k = bb / 512, rem = bb % 512;
      int kb = rem / 16, n0 = (rem % 16) * 32;
      src = W1 + (size_t)k * DIN * DH + (size_t)kb * 32 * DH + n0;
      dst = W1p + (((size_t)(k * 32 + kb) * 512 + n0) * 32);
    } else {
      int b2 = bb - W1_TILES;
      int k = b2 / 256, rem = b2 % 256;
      int kb = rem / 16, n0 = (rem % 16) * 32;
      src = W2 + (size_t)k * DH * DH + (size_t)kb * 32 * DH + n0;
      dst = W2p + (((size_t)(k * 16 + kb) * 512 + n0) * 32);
    }
    {
      int ki = t >> 3, n4 = (t & 7) * 4;
      float4 v = *(const float4*)&src[(size_t)ki * DH + n4];
      tile[ki][n4 + 0] = f2bf(v.x);
      tile[ki][n4 + 1] = f2bf(v.y);
      tile[ki][n4 + 2] = f2bf(v.z);
      tile[ki][n4 + 3] = f2bf(v.w);
    }
    __syncthreads();
    {
      int n = t >> 3, ki = (t & 7) * 4;
      U16x4 o = {tile[ki + 0][n], tile[ki + 1][n], tile[ki + 2][n],
                 tile[ki + 3][n]};
      *(U16x4*)&dst[(size_t)n * 32 + ki] = o;
    }
  }
}

// Fused phi: h1 = relu(x@W1[k]+b1) entirely in LDS, then
// psum[k] += relu(h1@W2[k]+b2) masked. grid 266 compact chunks (TM=32 rows,
// full 512 cols). Wave w owns cols [w*128, w*128+128): acc 2m x 8nt.
// B prefetch: double-buffered per-ks (8 frags in flight vs 16 MFMAs).
__global__ __launch_bounds__(256) void phi_kernel(
    const float* __restrict__ x, const u16* __restrict__ W1p,
    const u16* __restrict__ W2p, const float* __restrict__ b1,
    const float* __restrict__ b2, const int* __restrict__ cnt,
    const int* __restrict__ idxlist, float* __restrict__ psum) {
  // compact chunk decode: chunk -> (cluster k, slot base, valid rows)
  const int chunk = blockIdx.x;
  int k = -1, sbase = 0, valid = 0, cacc = 0;
#pragma unroll
  for (int kk = 0; kk < KC; ++kk) {
    int c = cnt[kk];
    int nch = (c + TM - 1) / TM;
    if (k < 0 && chunk < cacc + nch) {
      k = kk;
      int b = (chunk - cacc) * TM;
      sbase = b;
      valid = min(TM, c - b);
    }
    cacc += nch;
  }
  if (k < 0) return;

  const int tid = threadIdx.x;
  const int w = tid >> 6, lane = tid & 63;
  const int quad = lane >> 4, l16 = lane & 15;

  __shared__ __align__(16) u16 A_sh[TM * LDA];  // 33.3 KB (x half-rows)
  __shared__ __align__(16) u16 H_sh[TM * LDA];  // 33.3 KB (h1, stays on-chip)
  __shared__ int ridx[TM];
  if (tid < TM)
    ridx[tid] = (tid < valid) ? idxlist[k * NPATCH + sbase + tid] : -1;
  __syncthreads();

  const f32x4 zero4 = {0.f, 0.f, 0.f, 0.f};
  f32x4 acc[2][8];
#pragma unroll
  for (int m = 0; m < 2; ++m)
#pragma unroll
    for (int nt = 0; nt < 8; ++nt) acc[m][nt] = zero4;

  const int srow = tid >> 3;          // 32 rows, 8 thr/row
  const int sc0 = (tid & 7) * 4;      // float4 base col; +c*32 per iter
  const int asrc = ridx[srow];

  // ---- layer 1: K=1024 in two 512-halves ----
  for (int kh = 0; kh < 2; ++kh) {
    if (kh) __syncthreads();
    if (asrc >= 0) {
      const float* xr = x + (size_t)asrc * DIN + kh * 512;
#pragma unroll
      for (int c = 0; c < 16; ++c) {
        float4 v = *(const float4*)(xr + sc0 + c * 32);
        U16x4 o = {f2bf(v.x), f2bf(v.y), f2bf(v.z), f2bf(v.w)};
        *(U16x4*)&A_sh[srow * LDA + sc0 + c * 32] = o;
      }
    } else {
      U16x4 o = {0, 0, 0, 0};
#pragma unroll
      for (int c = 0; c < 16; ++c)
        *(U16x4*)&A_sh[srow * LDA + sc0 + c * 32] = o;
    }
    __syncthreads();

    // B: col = w*128 + nt*16 + l16; ks stride 16384 u16, nt stride 512 u16
    const u16* wb = W1p + ((size_t)(k * 32 + kh * 16) * 512 +
                           (w * 128 + l16)) * 32 + quad * 8;
    bf16x8 B[2][8];
#pragma unroll
    for (int nt = 0; nt < 8; ++nt)
      B[0][nt] = *(const bf16x8*)(wb + (size_t)nt * 512);
#pragma unroll
    for (int ks = 0; ks < 16; ++ks) {
      const int cur = ks & 1, nxt = cur ^ 1;
      if (ks < 15) {
#pragma unroll
        for (int nt = 0; nt < 8; ++nt)
          B[nxt][nt] =
              *(const bf16x8*)(wb + (size_t)(ks + 1) * 16384 + nt * 512);
      }
      bf16x8 af0 = *(const bf16x8*)&A_sh[l16 * LDA + ks * 32 + quad * 8];
      bf16x8 af1 =
          *(const bf16x8*)&A_sh[(16 + l16) * LDA + ks * 32 + quad * 8];
#pragma unroll
      for (int nt = 0; nt < 8; ++nt) {
        acc[0][nt] = __builtin_amdgcn_mfma_f32_16x16x32_bf16(af0, B[cur][nt],
                                                             acc[0][nt], 0, 0, 0);
        acc[1][nt] = __builtin_amdgcn_mfma_f32_16x16x32_bf16(af1, B[cur][nt],
                                                             acc[1][nt], 0, 0, 0);
      }
    }
  }

  // h1 epilogue: bias+relu -> H_sh, DIRECT C-layout write (row=quad*4+r,
  // col=own col) -- already A-operand-ready for layer 2. No global trip.
#pragma unroll
  for (int m = 0; m < 2; ++m)
#pragma unroll
    for (int nt = 0; nt < 8; ++nt) {
      int c = w * 128 + nt * 16 + l16;
      float bias = b1[k * DH + c];
#pragma unroll
      for (int r = 0; r < 4; ++r) {
        int row = m * 16 + quad * 4 + r;
        H_sh[row * LDA + c] = f2bf(fmaxf(acc[m][nt][r] + bias, 0.f));
      }
    }
  __syncthreads();

  // ---- layer 2: K=512 from H_sh ----
#pragma unroll
  for (int m = 0; m < 2; ++m)
#pragma unroll
    for (int nt = 0; nt < 8; ++nt) acc[m][nt] = zero4;

  const u16* wb2 = W2p + ((size_t)(k * 16) * 512 + (w * 128 + l16)) * 32 +
                   quad * 8;
  bf16x8 B2[2][8];
#pragma unroll
  for (int nt = 0; nt < 8; ++nt)
    B2[0][nt] = *(const bf16x8*)(wb2 + (size_t)nt * 512);
#pragma unroll
  for (int ks = 0; ks < 16; ++ks) {
    const int cur = ks & 1, nxt = cur ^ 1;
    if (ks < 15) {
#pragma unroll
      for (int nt = 0; nt < 8; ++nt)
        B2[nxt][nt] =
            *(const bf16x8*)(wb2 + (size_t)(ks + 1) * 16384 + nt * 512);
    }
    bf16x8 af0 = *(const bf16x8*)&H_sh[l16 * LDA + ks * 32 + quad * 8];
    bf16x8 af1 = *(const bf16x8*)&H_sh[(16 + l16) * LDA + ks * 32 + quad * 8];
#pragma unroll
    for (int nt = 0; nt < 8; ++nt) {
      acc[0][nt] = __builtin_amdgcn_mfma_f32_16x16x32_bf16(af0, B2[cur][nt],
                                                           acc[0][nt], 0, 0, 0);
      acc[1][nt] = __builtin_amdgcn_mfma_f32_16x16x32_bf16(af1, B2[cur][nt],
                                                           acc[1][nt], 0, 0, 0);
    }
  }

  // pool epilogue: bias+relu, mask padded rows, column-sum, atomic into psum
  float vmask[2][4];
#pragma unroll
  for (int m = 0; m < 2; ++m)
#pragma unroll
    for (int r = 0; r < 4; ++r)
      vmask[m][r] = (m * 16 + quad * 4 + r < valid) ? 1.f : 0.f;

#pragma unroll
  for (int nt = 0; nt < 8; ++nt) {
    int col = w * 128 + nt * 16 + l16;
    float bias = b2[k * DH + col];
    float s = 0.f;
#pragma unroll
    for (int m = 0; m < 2; ++m)
#pragma unroll
      for (int r = 0; r < 4; ++r)
        s += vmask[m][r] * fmaxf(acc[m][nt][r] + bias, 0.f);
    s += __shfl_xor(s, 16, 64);
    s += __shfl_xor(s, 32, 64);
    if (quad == 0) atomicAdd(&psum[k * DH + col], s);
  }
}

// Device-scope spin barrier across the head kernel's 32 co-resident blocks.
__device__ __forceinline__ void gsync(int* bar) {
  __syncthreads();
  if (threadIdx.x == 0) {
    __threadfence();
    atomicAdd(bar, 1);
    while (__hip_atomic_load(bar, __ATOMIC_RELAXED,
                             __HIP_MEMORY_SCOPE_AGENT) < 32) {
      __builtin_amdgcn_s_sleep(1);
    }
    __threadfence();
  }
  __syncthreads();
}

// Fused head: fc -> attn -> rho -> cls in ONE kernel (3 spin barriers).
__global__ __launch_bounds__(256) void head_kernel(
    const float* __restrict__ psum, const int* __restrict__ cnt,
    const float* __restrict__ fcW, const float* __restrict__ fcb,
    const float* __restrict__ Va, const float* __restrict__ ba,
    const float* __restrict__ Vb, const float* __restrict__ bb_,
    const float* __restrict__ Vc, const float* __restrict__ rhoW,
    const float* __restrict__ rhob, const float* __restrict__ clsW,
    const float* __restrict__ clsb, float* __restrict__ hstore,
    float* __restrict__ sstore, float* __restrict__ h2g, int* __restrict__ bar,
    float* __restrict__ out) {
  __shared__ __align__(16) float smem[10496];  // 42 KB, re-aliased per phase
  const int tid = threadIdx.x;
  const int blk = blockIdx.x;

  // ---- phase 1: fc (32 blocks x 16 cols) ----
  {
    float* p_sh = smem;
    float* red = smem + 5120;
    float* invs = smem + 7680;
    const int j0 = blk * 16;
    const int j = tid & 15, dq = tid >> 4;
    if (tid < KC) {
      int c = cnt[tid];
      invs[tid] = (c > 0) ? 1.f / (float)c : 0.f;
    }
    __syncthreads();
#pragma unroll
    for (int it = 0; it < KC * DH / 256; ++it) {
      int e = it * 256 + tid;
      p_sh[e] = psum[e] * invs[e >> 9];
    }
    __syncthreads();
    float acc[KC];
#pragma unroll
    for (int k = 0; k < KC; ++k) acc[k] = 0.f;
#pragma unroll 8
    for (int i = 0; i < 32; ++i) {
      int ii = (i + dq) & 31;
      int d = dq * 32 + ii;
      float wv = fcW[(size_t)d * DH + j0 + j];
#pragma unroll
      for (int k = 0; k < KC; ++k)
        acc[k] = fmaf(p_sh[k * DH + d], wv, acc[k]);
    }
#pragma unroll
    for (int k = 0; k < KC; ++k) red[(dq * 16 + j) * KC + k] = acc[k];
    __syncthreads();
    if (tid < 16 * KC) {
      int jj = tid / KC, k = tid % KC;
      float s = 0.f;
#pragma unroll
      for (int q = 0; q < 16; ++q) s += red[(q * 16 + jj) * KC + k];
      hstore[k * DH + j0 + jj] = fmaxf(s + fcb[j0 + jj], 0.f);
    }
  }
  gsync(&bar[0]);

  // ---- phase 2: gated attention (blocks 0..15, 16 cols each) ----
  if (blk < 16) {
    float* h_sh = smem;
    float* reda = smem + 5120;
    float* redb = smem + 7680;
    float* gred = smem + 10240;
    const int j0 = blk * 16;
    const int j = tid & 15, dq = tid >> 4;
#pragma unroll
    for (int it = 0; it < KC * DH / 256; ++it) {
      int e = it * 256 + tid;
      h_sh[e] = hstore[e];
    }
    __syncthreads();
    float sa[KC], sb[KC];
#pragma unroll
    for (int k = 0; k < KC; ++k) { sa[k] = 0.f; sb[k] = 0.f; }
#pragma unroll 8
    for (int i = 0; i < 32; ++i) {
      int ii = (i + dq) & 31;
      int d = dq * 32 + ii;
      float va = Va[(size_t)d * DA + j0 + j];
      float vb = Vb[(size_t)d * DA + j0 + j];
#pragma unroll
      for (int k = 0; k < KC; ++k) {
        float h = h_sh[k * DH + d];
        sa[k] = fmaf(h, va, sa[k]);
        sb[k] = fmaf(h, vb, sb[k]);
      }
    }
#pragma unroll
    for (int k = 0; k < KC; ++k) {
      reda[(dq * 16 + j) * KC + k] = sa[k];
      redb[(dq * 16 + j) * KC + k] = sb[k];
    }
    __syncthreads();
    if (tid < 16 * KC) {
      int jj = tid / KC, k = tid % KC;
      float ta = 0.f, tb = 0.f;
#pragma unroll
      for (int q = 0; q < 16; ++q) {
        ta += reda[(q * 16 + jj) * KC + k];
        tb += redb[(q * 16 + jj) * KC + k];
      }
      float a = tanhf(ta + ba[j0 + jj]);
      float b = 1.f / (1.f + expf(-(tb + bb_[j0 + jj])));
      gred[jj * KC + k] = a * b * Vc[j0 + jj];  // bc dropped: softmax shift-inv
    }
    __syncthreads();
    if (tid < KC) {
      float s = 0.f;
#pragma unroll
      for (int jj = 0; jj < 16; ++jj) s += gred[jj * KC + tid];
      atomicAdd(&sstore[tid], s);
    }
  }
  gsync(&bar[1]);

  // ---- phase 3: rho (blocks 0..7; softmax+h_path redundant per block) ----
  if (blk < 8) {
    float* ws_sh = smem;
    float* hp_sh = smem + 64;
    float* red = smem + 1024;
    const int j0 = blk * 32;
    const int j = tid & 31, dq = tid >> 5;
    if (tid == 0) {
      float sv[KC], m = -1e30f;
#pragma unroll
      for (int k = 0; k < KC; ++k) { sv[k] = sstore[k]; m = fmaxf(m, sv[k]); }
      float Z = 0.f;
#pragma unroll
      for (int k = 0; k < KC; ++k) { sv[k] = expf(sv[k] - m); Z += sv[k]; }
      float invZ = 1.f / Z;
#pragma unroll
      for (int k = 0; k < KC; ++k) ws_sh[k] = sv[k] * invZ;
    }
    __syncthreads();
#pragma unroll
    for (int it = 0; it < 2; ++it) {
      int d = it * 256 + tid;
      float s = 0.f;
#pragma unroll
      for (int k = 0; k < KC; ++k) s = fmaf(ws_sh[k], hstore[k * DH + d], s);
      hp_sh[d] = s;
    }
    __syncthreads();
    float acc = 0.f;
#pragma unroll 8
    for (int i = 0; i < 64; ++i) {
      int d = dq * 64 + i;
      acc = fmaf(hp_sh[d], rhoW[(size_t)d * DA + j0 + j], acc);
    }
    red[dq * 32 + j] = acc;
    __syncthreads();
    if (tid < 32) {
      float s = 0.f;
#pragma unroll
      for (int q = 0; q < 8; ++q) s += red[q * 32 + tid];
      h2g[j0 + tid] = fmaxf(s + rhob[j0 + tid], 0.f);
    }
  }
  gsync(&bar[2]);

  // ---- phase 4: classifier (block 0) ----
  if (blk == 0) {
    float* rd = smem;
    float h = h2g[tid];
#pragma unroll
    for (int c = 0; c < NCLS; ++c) rd[c * 256 + tid] = h * clsW[tid * NCLS + c];
    __syncthreads();
    for (int s = 128; s > 0; s >>= 1) {
      if (tid < s) {
#pragma unroll
        for (int c = 0; c < NCLS; ++c)
          rd[c * 256 + tid] += rd[c * 256 + tid + s];
      }
      __syncthreads();
    }
    if (tid == 0) {
      float lg[NCLS], hz[NCLS];
      int best = 0;
#pragma unroll
      for (int c = 0; c < NCLS; ++c) {
        lg[c] = rd[c * 256] + clsb[c];
        hz[c] = 1.f / (1.f + expf(-lg[c]));
        if (lg[c] > lg[best]) best = c;
      }
      float S = 1.f;
#pragma unroll
      for (int c = 0; c < NCLS; ++c) out[c] = hz[c];
#pragma unroll
      for (int c = 0; c < NCLS; ++c) {
        S *= (1.f - hz[c]);
        out[NCLS + c] = S;
      }
      out[2 * NCLS] = (float)best;
    }
  }
}

extern "C" void kernel_launch(void* const* d_in, const int* in_sizes, int n_in,
                              void* d_out, int out_size, void* d_ws,
                              size_t ws_size, hipStream_t stream) {
  const float* x    = (const float*)d_in[0];
  const int*   cid  = (const int*)d_in[1];
  const float* W1   = (const float*)d_in[2];
  const float* b1   = (const float*)d_in[3];
  const float* W2   = (const float*)d_in[4];
  const float* b2   = (const float*)d_in[5];
  const float* fcW  = (const float*)d_in[6];
  const float* fcb  = (const float*)d_in[7];
  const float* Va   = (const float*)d_in[8];
  const float* ba   = (const float*)d_in[9];
  const float* Vb   = (const float*)d_in[10];
  const float* bb_  = (const float*)d_in[11];
  const float* Vc   = (const float*)d_in[12];
  const float* rhoW = (const float*)d_in[14];
  const float* rhob = (const float*)d_in[15];
  const float* clsW = (const float*)d_in[16];
  const float* clsb = (const float*)d_in[17];
  float* out = (float*)d_out;

  char* ws = (char*)d_ws;
  int*   cnt     = (int*)(ws + OFF_CNT);
  int*   bar     = (int*)(ws + OFF_BAR);
  int*   idxlist = (int*)(ws + OFF_IDX);
  float* psum    = (float*)(ws + OFF_PSUM);
  float* hstore  = (float*)(ws + OFF_H);
  float* sstore  = (float*)(ws + OFF_S);
  float* h2g     = (float*)(ws + OFF_H2);
  u16*   W1p     = (u16*)(ws + OFF_W1P);
  u16*   W2p     = (u16*)(ws + OFF_W2P);

  (void)hipMemsetAsync(cnt, 0, 64, stream);  // zeroes cnt[10] + bar[3]
  prep_kernel<<<NB_PREP, 256, 0, stream>>>(cid, cnt, idxlist, W1, W2, W1p, W2p,
                                           psum, sstore);
  // max chunks: 8192/32 + (KC-1) partial = 266
  phi_kernel<<<266, 256, 0, stream>>>(x, W1p, W2p, b1, b2, cnt, idxlist, psum);
  head_kernel<<<32, 256, 0, stream>>>(psum, cnt, fcW, fcb, Va, ba, Vb, bb_, Vc,
                                      rhoW, rhob, clsW, clsb, hstore, sstore,
                                      h2g, bar, out);
}

// Round 11
// 202.266 us; speedup vs baseline: 1.0598x; 1.0598x over previous
//
#include <hip/hip_runtime.h>
#include <math.h>

// Problem constants (from reference)
#define NPATCH 8192
#define KC     10
#define DIN    1024
#define DH     512
#define DA     256
#define NCLS   4

#define TM  32    // patches per phi block (full 512-col width per block)
#define LDA 520   // padded LDS row stride (u16)

typedef unsigned short u16;
typedef short bf16x8 __attribute__((ext_vector_type(8)));   // 8 bf16 = 4 VGPRs
typedef float f32x4  __attribute__((ext_vector_type(4)));

// Workspace layout (bytes)
#define OFF_CNT   0                  // int[KC] (40B) + bar[3] @40; 64B memset covers
#define OFF_BAR   40
#define OFF_IDX   64                 // int[KC*NPATCH] sparse (k*NPATCH+slot)
#define OFF_PSUM  327744             // float[KC*DH]
#define OFF_H     348224             // float[KC*DH]
#define OFF_S     368704             // float[KC]
#define OFF_H2    368768             // float[DA]
#define OFF_W1P   369792             // u16[KC*DIN*DH]
#define OFF_W2P   10855552           // u16[KC*DH*DH]
// total ~16.1 MB

__device__ __forceinline__ u16 f2bf(float f) {
  union { float f; unsigned u; } v; v.f = f;
  unsigned r = (v.u + 0x7fffu + ((v.u >> 16) & 1u)) >> 16;  // RNE
  return (u16)r;
}

struct __align__(8) U16x4 { u16 x, y, z, w; };

#define W1_TILES (KC * (DIN / 32) * (DH / 32))  // 5120
#define W2_TILES (KC * (DH / 32) * (DH / 32))   // 2560
#define NB_BUCKET 32
#define NB_PREP   (NB_BUCKET + W1_TILES + W2_TILES)  // 7712

// prep: bucket + zero psum/sstore (blocks 0..31), pack W1/W2 -> bf16 MFMA-B
// panels [k][kb][n][ki].
__global__ __launch_bounds__(256) void prep_kernel(
    const int* __restrict__ cid, int* __restrict__ cnt,
    int* __restrict__ idxlist, const float* __restrict__ W1,
    const float* __restrict__ W2, u16* __restrict__ W1p,
    u16* __restrict__ W2p, float* __restrict__ psum,
    float* __restrict__ sstore) {
  int b = blockIdx.x, t = threadIdx.x;
  if (b < NB_BUCKET) {
    int g = b * 256 + t;
    if (g < KC * DH) psum[g] = 0.f;
    if (g < KC) sstore[g] = 0.f;
    __shared__ int lcnt[KC], lbase[KC];
    if (t < KC) lcnt[t] = 0;
    __syncthreads();
    int n = b * 256 + t;                 // NPATCH == 32*256
    int k = cid[n];
    int myoff = atomicAdd(&lcnt[k], 1);
    __syncthreads();
    if (t < KC) lbase[t] = atomicAdd(&cnt[t], lcnt[t]);
    __syncthreads();
    idxlist[k * NPATCH + lbase[k] + myoff] = n;
  } else {
    __shared__ u16 tile[32][33];
    int bb = b - NB_BUCKET;
    const float* src;
    u16* dst;
    if (bb < W1_TILES) {
      int k = bb / 512, rem = bb % 512;
      int kb = rem / 16, n0 = (rem % 16) * 32;
      src = W1 + (size_t)k * DIN * DH + (size_t)kb * 32 * DH + n0;
      dst = W1p + (((size_t)(k * 32 + kb) * 512 + n0) * 32);
    } else {
      int b2 = bb - W1_TILES;
      int k = b2 / 256, rem = b2 % 256;
      int kb = rem / 16, n0 = (rem % 16) * 32;
      src = W2 + (size_t)k * DH * DH + (size_t)kb * 32 * DH + n0;
      dst = W2p + (((size_t)(k * 16 + kb) * 512 + n0) * 32);
    }
    {
      int ki = t >> 3, n4 = (t & 7) * 4;
      float4 v = *(const float4*)&src[(size_t)ki * DH + n4];
      tile[ki][n4 + 0] = f2bf(v.x);
      tile[ki][n4 + 1] = f2bf(v.y);
      tile[ki][n4 + 2] = f2bf(v.z);
      tile[ki][n4 + 3] = f2bf(v.w);
    }
    __syncthreads();
    {
      int n = t >> 3, ki = (t & 7) * 4;
      U16x4 o = {tile[ki + 0][n], tile[ki + 1][n], tile[ki + 2][n],
                 tile[ki + 3][n]};
      *(U16x4*)&dst[(size_t)n * 32 + ki] = o;
    }
  }
}

// Fused phi, 512 threads = 8 waves: h1 in LDS, depth-2 B prefetch.
// Wave w owns 64 cols (acc 2m x 4nt). grid 266 compact chunks.
__global__ __launch_bounds__(512) void phi_kernel(
    const float* __restrict__ x, const u16* __restrict__ W1p,
    const u16* __restrict__ W2p, const float* __restrict__ b1,
    const float* __restrict__ b2, const int* __restrict__ cnt,
    const int* __restrict__ idxlist, float* __restrict__ psum) {
  const int chunk = blockIdx.x;
  int k = -1, sbase = 0, valid = 0, cacc = 0;
#pragma unroll
  for (int kk = 0; kk < KC; ++kk) {
    int c = cnt[kk];
    int nch = (c + TM - 1) / TM;
    if (k < 0 && chunk < cacc + nch) {
      k = kk;
      int b = (chunk - cacc) * TM;
      sbase = b;
      valid = min(TM, c - b);
    }
    cacc += nch;
  }
  if (k < 0) return;

  const int tid = threadIdx.x;
  const int w = tid >> 6, lane = tid & 63;
  const int quad = lane >> 4, l16 = lane & 15;

  __shared__ __align__(16) u16 A_sh[TM * LDA];  // 33.3 KB
  __shared__ __align__(16) u16 H_sh[TM * LDA];  // 33.3 KB
  __shared__ int ridx[TM];
  if (tid < TM)
    ridx[tid] = (tid < valid) ? idxlist[k * NPATCH + sbase + tid] : -1;
  __syncthreads();

  const f32x4 zero4 = {0.f, 0.f, 0.f, 0.f};
  f32x4 acc[2][4];
#pragma unroll
  for (int m = 0; m < 2; ++m)
#pragma unroll
    for (int nt = 0; nt < 4; ++nt) acc[m][nt] = zero4;

  const int srow = tid >> 4;          // 32 rows, 16 thr/row
  const int sc0 = (tid & 15) * 4;     // float4 base col; +c*64 per iter
  const int asrc = ridx[srow];

  // ---- layer 1: K=1024 in two 512-halves ----
  for (int kh = 0; kh < 2; ++kh) {
    if (kh) __syncthreads();
    if (asrc >= 0) {
      const float* xr = x + (size_t)asrc * DIN + kh * 512;
#pragma unroll
      for (int c = 0; c < 8; ++c) {
        float4 v = *(const float4*)(xr + sc0 + c * 64);
        U16x4 o = {f2bf(v.x), f2bf(v.y), f2bf(v.z), f2bf(v.w)};
        *(U16x4*)&A_sh[srow * LDA + sc0 + c * 64] = o;
      }
    } else {
      U16x4 o = {0, 0, 0, 0};
#pragma unroll
      for (int c = 0; c < 8; ++c)
        *(U16x4*)&A_sh[srow * LDA + sc0 + c * 64] = o;
    }
    __syncthreads();

    // B: col = w*64 + nt*16 + l16; ks stride 16384 u16, nt stride 512 u16
    const u16* wb = W1p + ((size_t)(k * 32 + kh * 16) * 512 +
                           (w * 64 + l16)) * 32 + quad * 8;
    bf16x8 B[3][4];
#pragma unroll
    for (int nt = 0; nt < 4; ++nt) {
      B[0][nt] = *(const bf16x8*)(wb + (size_t)nt * 512);
      B[1][nt] = *(const bf16x8*)(wb + (size_t)16384 + nt * 512);
    }
#pragma unroll
    for (int ks = 0; ks < 16; ++ks) {
      const int cur = ks % 3;
      if (ks < 14) {
        const int pf = (ks + 2) % 3;
#pragma unroll
        for (int nt = 0; nt < 4; ++nt)
          B[pf][nt] =
              *(const bf16x8*)(wb + (size_t)(ks + 2) * 16384 + nt * 512);
      }
      bf16x8 af0 = *(const bf16x8*)&A_sh[l16 * LDA + ks * 32 + quad * 8];
      bf16x8 af1 =
          *(const bf16x8*)&A_sh[(16 + l16) * LDA + ks * 32 + quad * 8];
#pragma unroll
      for (int nt = 0; nt < 4; ++nt) {
        acc[0][nt] = __builtin_amdgcn_mfma_f32_16x16x32_bf16(af0, B[cur][nt],
                                                             acc[0][nt], 0, 0, 0);
        acc[1][nt] = __builtin_amdgcn_mfma_f32_16x16x32_bf16(af1, B[cur][nt],
                                                             acc[1][nt], 0, 0, 0);
      }
    }
  }

  // h1 epilogue: bias+relu -> H_sh in direct C-layout (A-operand-ready)
#pragma unroll
  for (int m = 0; m < 2; ++m)
#pragma unroll
    for (int nt = 0; nt < 4; ++nt) {
      int c = w * 64 + nt * 16 + l16;
      float bias = b1[k * DH + c];
#pragma unroll
      for (int r = 0; r < 4; ++r) {
        int row = m * 16 + quad * 4 + r;
        H_sh[row * LDA + c] = f2bf(fmaxf(acc[m][nt][r] + bias, 0.f));
      }
    }
  __syncthreads();

  // ---- layer 2: K=512 from H_sh ----
#pragma unroll
  for (int m = 0; m < 2; ++m)
#pragma unroll
    for (int nt = 0; nt < 4; ++nt) acc[m][nt] = zero4;

  const u16* wb2 =
      W2p + ((size_t)(k * 16) * 512 + (w * 64 + l16)) * 32 + quad * 8;
  bf16x8 B2[3][4];
#pragma unroll
  for (int nt = 0; nt < 4; ++nt) {
    B2[0][nt] = *(const bf16x8*)(wb2 + (size_t)nt * 512);
    B2[1][nt] = *(const bf16x8*)(wb2 + (size_t)16384 + nt * 512);
  }
#pragma unroll
  for (int ks = 0; ks < 16; ++ks) {
    const int cur = ks % 3;
    if (ks < 14) {
      const int pf = (ks + 2) % 3;
#pragma unroll
      for (int nt = 0; nt < 4; ++nt)
        B2[pf][nt] =
            *(const bf16x8*)(wb2 + (size_t)(ks + 2) * 16384 + nt * 512);
    }
    bf16x8 af0 = *(const bf16x8*)&H_sh[l16 * LDA + ks * 32 + quad * 8];
    bf16x8 af1 = *(const bf16x8*)&H_sh[(16 + l16) * LDA + ks * 32 + quad * 8];
#pragma unroll
    for (int nt = 0; nt < 4; ++nt) {
      acc[0][nt] = __builtin_amdgcn_mfma_f32_16x16x32_bf16(af0, B2[cur][nt],
                                                           acc[0][nt], 0, 0, 0);
      acc[1][nt] = __builtin_amdgcn_mfma_f32_16x16x32_bf16(af1, B2[cur][nt],
                                                           acc[1][nt], 0, 0, 0);
    }
  }

  // pool epilogue: bias+relu, mask padded rows, column-sum, atomic into psum
  float vmask[2][4];
#pragma unroll
  for (int m = 0; m < 2; ++m)
#pragma unroll
    for (int r = 0; r < 4; ++r)
      vmask[m][r] = (m * 16 + quad * 4 + r < valid) ? 1.f : 0.f;

#pragma unroll
  for (int nt = 0; nt < 4; ++nt) {
    int col = w * 64 + nt * 16 + l16;
    float bias = b2[k * DH + col];
    float s = 0.f;
#pragma unroll
    for (int m = 0; m < 2; ++m)
#pragma unroll
      for (int r = 0; r < 4; ++r)
        s += vmask[m][r] * fmaxf(acc[m][nt][r] + bias, 0.f);
    s += __shfl_xor(s, 16, 64);
    s += __shfl_xor(s, 32, 64);
    if (quad == 0) atomicAdd(&psum[k * DH + col], s);
  }
}

// Device-scope spin barrier across the head kernel's 32 co-resident blocks.
__device__ __forceinline__ void gsync(int* bar) {
  __syncthreads();
  if (threadIdx.x == 0) {
    __threadfence();
    atomicAdd(bar, 1);
    while (__hip_atomic_load(bar, __ATOMIC_RELAXED,
                             __HIP_MEMORY_SCOPE_AGENT) < 32) {
      __builtin_amdgcn_s_sleep(1);
    }
    __threadfence();
  }
  __syncthreads();
}

// Fused head: fc -> attn -> rho -> cls in ONE kernel (3 spin barriers).
__global__ __launch_bounds__(256) void head_kernel(
    const float* __restrict__ psum, const int* __restrict__ cnt,
    const float* __restrict__ fcW, const float* __restrict__ fcb,
    const float* __restrict__ Va, const float* __restrict__ ba,
    const float* __restrict__ Vb, const float* __restrict__ bb_,
    const float* __restrict__ Vc, const float* __restrict__ rhoW,
    const float* __restrict__ rhob, const float* __restrict__ clsW,
    const float* __restrict__ clsb, float* __restrict__ hstore,
    float* __restrict__ sstore, float* __restrict__ h2g, int* __restrict__ bar,
    float* __restrict__ out) {
  __shared__ __align__(16) float smem[10496];  // 42 KB, re-aliased per phase
  const int tid = threadIdx.x;
  const int blk = blockIdx.x;

  // ---- phase 1: fc (32 blocks x 16 cols) ----
  {
    float* p_sh = smem;
    float* red = smem + 5120;
    float* invs = smem + 7680;
    const int j0 = blk * 16;
    const int j = tid & 15, dq = tid >> 4;
    if (tid < KC) {
      int c = cnt[tid];
      invs[tid] = (c > 0) ? 1.f / (float)c : 0.f;
    }
    __syncthreads();
#pragma unroll
    for (int it = 0; it < KC * DH / 256; ++it) {
      int e = it * 256 + tid;
      p_sh[e] = psum[e] * invs[e >> 9];
    }
    __syncthreads();
    float acc[KC];
#pragma unroll
    for (int k = 0; k < KC; ++k) acc[k] = 0.f;
#pragma unroll 8
    for (int i = 0; i < 32; ++i) {
      int ii = (i + dq) & 31;
      int d = dq * 32 + ii;
      float wv = fcW[(size_t)d * DH + j0 + j];
#pragma unroll
      for (int k = 0; k < KC; ++k)
        acc[k] = fmaf(p_sh[k * DH + d], wv, acc[k]);
    }
#pragma unroll
    for (int k = 0; k < KC; ++k) red[(dq * 16 + j) * KC + k] = acc[k];
    __syncthreads();
    if (tid < 16 * KC) {
      int jj = tid / KC, k = tid % KC;
      float s = 0.f;
#pragma unroll
      for (int q = 0; q < 16; ++q) s += red[(q * 16 + jj) * KC + k];
      hstore[k * DH + j0 + jj] = fmaxf(s + fcb[j0 + jj], 0.f);
    }
  }
  gsync(&bar[0]);

  // ---- phase 2: gated attention (blocks 0..15, 16 cols each) ----
  if (blk < 16) {
    float* h_sh = smem;
    float* reda = smem + 5120;
    float* redb = smem + 7680;
    float* gred = smem + 10240;
    const int j0 = blk * 16;
    const int j = tid & 15, dq = tid >> 4;
#pragma unroll
    for (int it = 0; it < KC * DH / 256; ++it) {
      int e = it * 256 + tid;
      h_sh[e] = hstore[e];
    }
    __syncthreads();
    float sa[KC], sb[KC];
#pragma unroll
    for (int k = 0; k < KC; ++k) { sa[k] = 0.f; sb[k] = 0.f; }
#pragma unroll 8
    for (int i = 0; i < 32; ++i) {
      int ii = (i + dq) & 31;
      int d = dq * 32 + ii;
      float va = Va[(size_t)d * DA + j0 + j];
      float vb = Vb[(size_t)d * DA + j0 + j];
#pragma unroll
      for (int k = 0; k < KC; ++k) {
        float h = h_sh[k * DH + d];
        sa[k] = fmaf(h, va, sa[k]);
        sb[k] = fmaf(h, vb, sb[k]);
      }
    }
#pragma unroll
    for (int k = 0; k < KC; ++k) {
      reda[(dq * 16 + j) * KC + k] = sa[k];
      redb[(dq * 16 + j) * KC + k] = sb[k];
    }
    __syncthreads();
    if (tid < 16 * KC) {
      int jj = tid / KC, k = tid % KC;
      float ta = 0.f, tb = 0.f;
#pragma unroll
      for (int q = 0; q < 16; ++q) {
        ta += reda[(q * 16 + jj) * KC + k];
        tb += redb[(q * 16 + jj) * KC + k];
      }
      float a = tanhf(ta + ba[j0 + jj]);
      float b = 1.f / (1.f + expf(-(tb + bb_[j0 + jj])));
      gred[jj * KC + k] = a * b * Vc[j0 + jj];  // bc dropped: softmax shift-inv
    }
    __syncthreads();
    if (tid < KC) {
      float s = 0.f;
#pragma unroll
      for (int jj = 0; jj < 16; ++jj) s += gred[jj * KC + tid];
      atomicAdd(&sstore[tid], s);
    }
  }
  gsync(&bar[1]);

  // ---- phase 3: rho (blocks 0..7; softmax+h_path redundant per block) ----
  if (blk < 8) {
    float* ws_sh = smem;
    float* hp_sh = smem + 64;
    float* red = smem + 1024;
    const int j0 = blk * 32;
    const int j = tid & 31, dq = tid >> 5;
    if (tid == 0) {
      float sv[KC], m = -1e30f;
#pragma unroll
      for (int k = 0; k < KC; ++k) { sv[k] = sstore[k]; m = fmaxf(m, sv[k]); }
      float Z = 0.f;
#pragma unroll
      for (int k = 0; k < KC; ++k) { sv[k] = expf(sv[k] - m); Z += sv[k]; }
      float invZ = 1.f / Z;
#pragma unroll
      for (int k = 0; k < KC; ++k) ws_sh[k] = sv[k] * invZ;
    }
    __syncthreads();
#pragma unroll
    for (int it = 0; it < 2; ++it) {
      int d = it * 256 + tid;
      float s = 0.f;
#pragma unroll
      for (int k = 0; k < KC; ++k) s = fmaf(ws_sh[k], hstore[k * DH + d], s);
      hp_sh[d] = s;
    }
    __syncthreads();
    float acc = 0.f;
#pragma unroll 8
    for (int i = 0; i < 64; ++i) {
      int d = dq * 64 + i;
      acc = fmaf(hp_sh[d], rhoW[(size_t)d * DA + j0 + j], acc);
    }
    red[dq * 32 + j] = acc;
    __syncthreads();
    if (tid < 32) {
      float s = 0.f;
#pragma unroll
      for (int q = 0; q < 8; ++q) s += red[q * 32 + tid];
      h2g[j0 + tid] = fmaxf(s + rhob[j0 + tid], 0.f);
    }
  }
  gsync(&bar[2]);

  // ---- phase 4: classifier (block 0) ----
  if (blk == 0) {
    float* rd = smem;
    float h = h2g[tid];
#pragma unroll
    for (int c = 0; c < NCLS; ++c) rd[c * 256 + tid] = h * clsW[tid * NCLS + c];
    __syncthreads();
    for (int s = 128; s > 0; s >>= 1) {
      if (tid < s) {
#pragma unroll
        for (int c = 0; c < NCLS; ++c)
          rd[c * 256 + tid] += rd[c * 256 + tid + s];
      }
      __syncthreads();
    }
    if (tid == 0) {
      float lg[NCLS], hz[NCLS];
      int best = 0;
#pragma unroll
      for (int c = 0; c < NCLS; ++c) {
        lg[c] = rd[c * 256] + clsb[c];
        hz[c] = 1.f / (1.f + expf(-lg[c]));
        if (lg[c] > lg[best]) best = c;
      }
      float S = 1.f;
#pragma unroll
      for (int c = 0; c < NCLS; ++c) out[c] = hz[c];
#pragma unroll
      for (int c = 0; c < NCLS; ++c) {
        S *= (1.f - hz[c]);
        out[NCLS + c] = S;
      }
      out[2 * NCLS] = (float)best;
    }
  }
}

extern "C" void kernel_launch(void* const* d_in, const int* in_sizes, int n_in,
                              void* d_out, int out_size, void* d_ws,
                              size_t ws_size, hipStream_t stream) {
  const float* x    = (const float*)d_in[0];
  const int*   cid  = (const int*)d_in[1];
  const float* W1   = (const float*)d_in[2];
  const float* b1   = (const float*)d_in[3];
  const float* W2   = (const float*)d_in[4];
  const float* b2   = (const float*)d_in[5];
  const float* fcW  = (const float*)d_in[6];
  const float* fcb  = (const float*)d_in[7];
  const float* Va   = (const float*)d_in[8];
  const float* ba   = (const float*)d_in[9];
  const float* Vb   = (const float*)d_in[10];
  const float* bb_  = (const float*)d_in[11];
  const float* Vc   = (const float*)d_in[12];
  const float* rhoW = (const float*)d_in[14];
  const float* rhob = (const float*)d_in[15];
  const float* clsW = (const float*)d_in[16];
  const float* clsb = (const float*)d_in[17];
  float* out = (float*)d_out;

  char* ws = (char*)d_ws;
  int*   cnt     = (int*)(ws + OFF_CNT);
  int*   bar     = (int*)(ws + OFF_BAR);
  int*   idxlist = (int*)(ws + OFF_IDX);
  float* psum    = (float*)(ws + OFF_PSUM);
  float* hstore  = (float*)(ws + OFF_H);
  float* sstore  = (float*)(ws + OFF_S);
  float* h2g     = (float*)(ws + OFF_H2);
  u16*   W1p     = (u16*)(ws + OFF_W1P);
  u16*   W2p     = (u16*)(ws + OFF_W2P);

  (void)hipMemsetAsync(cnt, 0, 64, stream);  // zeroes cnt[10] + bar[3]
  prep_kernel<<<NB_PREP, 256, 0, stream>>>(cid, cnt, idxlist, W1, W2, W1p, W2p,
                                           psum, sstore);
  // max chunks: 8192/32 + (KC-1) partial = 266
  phi_kernel<<<266, 512, 0, stream>>>(x, W1p, W2p, b1, b2, cnt, idxlist, psum);
  head_kernel<<<32, 256, 0, stream>>>(psum, cnt, fcW, fcb, Va, ba, Vb, bb_, Vc,
                                      rhoW, rhob, clsW, clsb, hstore, sstore,
                                      h2g, bar, out);
}